// Round 3
// baseline (499.979 us; speedup 1.0000x reference)
//
#include <hip/hip_runtime.h>
#include <hip/hip_fp16.h>

#define BN_EPS 1e-5f
#define CHUNK 4096            // edges per histogram block

typedef _Float16 half8 __attribute__((ext_vector_type(8)));
typedef float f32x4 __attribute__((ext_vector_type(4)));

__device__ __forceinline__ float4 f4zero() { return make_float4(0.f, 0.f, 0.f, 0.f); }

// ---------------- K0: zero counts + cursors ----------------

__global__ __launch_bounds__(256) void k_zero(int4* __restrict__ p, int len4) {
    int i = blockIdx.x * 256 + threadIdx.x;
    if (i < len4) p[i] = make_int4(0, 0, 0, 0);
}

// ---------------- K1: packW(all 3) + degree histogram via global atomics ----------------

__global__ __launch_bounds__(256) void k_pack_hist(const float* __restrict__ W1,
                                                   const float* __restrict__ W2,
                                                   const float* __restrict__ W3,
                                                   _Float16* __restrict__ pW,
                                                   const int* __restrict__ dst,
                                                   int* __restrict__ counts, int e) {
    int tid = threadIdx.x;
    if (blockIdx.x < 24) {            // W pre-pack: f32 [128][128] -> f16 B-fragment order
        int t = blockIdx.x * 256 + tid;   // 0..6143
        int wi = t >> 11;
        int tt = t & 2047;
        const float* W = (wi == 0) ? W1 : ((wi == 1) ? W2 : W3);
        int kc = tt >> 9;
        int rem = tt & 511;
        int ct = rem >> 6;
        int lane = rem & 63;
        int q = lane >> 4;
        int col = ct * 16 + (lane & 15);
        half8 hh;
#pragma unroll
        for (int j = 0; j < 8; ++j)
            hh[j] = (_Float16)W[(kc * 32 + q * 8 + j) * 128 + col];
        *(half8*)(pW + (size_t)t * 8) = hh;
        return;
    }
    int base = (blockIdx.x - 24) * CHUNK;
    if (base + CHUNK <= e) {
        const int4* d4 = (const int4*)(dst + base);
#pragma unroll
        for (int t = 0; t < CHUNK / 1024; ++t) {
            int4 d = d4[t * 256 + tid];
            atomicAdd(&counts[d.x], 1);
            atomicAdd(&counts[d.y], 1);
            atomicAdd(&counts[d.z], 1);
            atomicAdd(&counts[d.w], 1);
        }
    } else {
        for (int i = base + tid; i < e; i += 256)
            atomicAdd(&counts[dst[i]], 1);
    }
}

// ---------------- K2/K3: scan of padded counts -> offs (+ dinv) ----------------

__global__ __launch_bounds__(1024) void k_scan_dinv(const int* __restrict__ counts,
                                                    int* __restrict__ offs,
                                                    float* __restrict__ dinv,
                                                    int* __restrict__ partials, int n) {
    __shared__ int s[1024];
    int t = threadIdx.x;
    int gid = blockIdx.x * 1024 + t;
    int c = (gid < n) ? counts[gid] : 0;
    if (gid < n) dinv[gid] = rsqrtf((float)(c + 1));
    int v = (c + 7) & ~7;                 // padded degree
    int x = v;
    s[t] = x;
    __syncthreads();
    for (int d = 1; d < 1024; d <<= 1) {
        int y = (t >= d) ? s[t - d] : 0;
        __syncthreads();
        x += y;
        s[t] = x;
        __syncthreads();
    }
    if (gid < n) offs[gid] = x - v;        // exclusive scan
    if (t == 1023) partials[blockIdx.x] = x;
}

// each 256-block self-sums the partials it needs
__global__ __launch_bounds__(256) void k_scan_addp(int* __restrict__ data,
                                                   const int* __restrict__ partials, int len) {
    __shared__ int red[256];
    int tid = threadIdx.x;
    int K = blockIdx.x >> 2;          // number of preceding 1024-segments
    int s = 0;
    for (int t = tid; t < K; t += 256) s += partials[t];
    red[tid] = s;
    __syncthreads();
    for (int d = 128; d > 0; d >>= 1) {
        if (tid < d) red[tid] += red[tid + d];
        __syncthreads();
    }
    int gid = blockIdx.x * 256 + tid;
    if (gid < len) data[gid] += red[0];
}

// ---------------- GEMM body (device): C[n,128](f16) = (A @ W) * dinv[row] ----------------

template <bool AF32>
__device__ __forceinline__ void gemm_body(int bid, int tid, char* smem,
                                          const void* __restrict__ Av,
                                          const _Float16* __restrict__ pW,
                                          const float* __restrict__ dinv,
                                          uint4* __restrict__ C, int n) {
    uint4* sW = (uint4*)smem;
    {
        const uint4* gW = (const uint4*)pW;
#pragma unroll
        for (int i = 0; i < 8; ++i) sW[tid + 256 * i] = gW[tid + 256 * i];
    }
    __syncthreads();

    int wave = tid >> 6, lane = tid & 63;
    int quad = lane >> 4, l16 = lane & 15;
    int row0 = bid * 64 + wave * 16;
    int arow = row0 + l16;
    int arowc = (arow < n) ? arow : (n - 1);

    half8 af[4];
    if (AF32) {
        const float* A = (const float*)Av + (size_t)arowc * 128 + quad * 8;
#pragma unroll
        for (int kc = 0; kc < 4; ++kc) {
            float4 lo = *(const float4*)(A + kc * 32);
            float4 hi = *(const float4*)(A + kc * 32 + 4);
            half8 h;
            h[0] = (_Float16)lo.x; h[1] = (_Float16)lo.y;
            h[2] = (_Float16)lo.z; h[3] = (_Float16)lo.w;
            h[4] = (_Float16)hi.x; h[5] = (_Float16)hi.y;
            h[6] = (_Float16)hi.z; h[7] = (_Float16)hi.w;
            af[kc] = h;
        }
    } else {
        const _Float16* A = (const _Float16*)Av + (size_t)arowc * 128 + quad * 8;
#pragma unroll
        for (int kc = 0; kc < 4; ++kc)
            af[kc] = *(const half8*)(A + kc * 32);
    }

    f32x4 acc[8];
#pragma unroll
    for (int ct = 0; ct < 8; ++ct) acc[ct] = (f32x4){0.f, 0.f, 0.f, 0.f};

#pragma unroll
    for (int kc = 0; kc < 4; ++kc) {
#pragma unroll
        for (int ct = 0; ct < 8; ++ct) {
            half8 bf = *(half8*)&sW[(kc * 8 + ct) * 64 + lane];
            acc[ct] = __builtin_amdgcn_mfma_f32_16x16x32_f16(af[kc], bf, acc[ct], 0, 0, 0);
        }
    }

    __syncthreads();

    _Float16* eb = (_Float16*)smem + wave * 16 * 136;   // 136 halfs = 272 B row stride
    float dv[4];
#pragma unroll
    for (int r = 0; r < 4; ++r) {
        int rr = row0 + quad * 4 + r;
        dv[r] = dinv[(rr < n) ? rr : (n - 1)];
    }
#pragma unroll
    for (int ct = 0; ct < 8; ++ct)
#pragma unroll
        for (int r = 0; r < 4; ++r)
            eb[(quad * 4 + r) * 136 + ct * 16 + l16] = (_Float16)(acc[ct][r] * dv[r]);

#pragma unroll
    for (int i = 0; i < 4; ++i) {
        int linear = i * 64 + lane;
        int r = linear >> 4, c = linear & 15;
        uint4 v = *(uint4*)((char*)eb + r * 272 + c * 16);
        int row = row0 + r;
        if (row < n) C[(size_t)row * 16 + c] = v;
    }
}

__global__ __launch_bounds__(256) void k_gemm_mfma(const void* __restrict__ Av,
                                                   const _Float16* __restrict__ pW,
                                                   const float* __restrict__ dinv,
                                                   uint4* __restrict__ C, int n) {
    __shared__ char smem[32768];
    gemm_body<false>(blockIdx.x, threadIdx.x, smem, Av, pW, dinv, C, n);
}

// ---------------- K4: place edges (+pad-fill, +pad-row zero, +GEMM1) blockIdx-split ------
// er stores BYTE offsets (src*256) so k_aggregate does 32-bit addressing.

__global__ __launch_bounds__(256) void k_place_gemm(const int* __restrict__ src,
                                                    const int* __restrict__ dst,
                                                    const int* __restrict__ counts,
                                                    int* __restrict__ offs,
                                                    int* __restrict__ cursor,
                                                    int* __restrict__ er,
                                                    unsigned int* __restrict__ bufAzero,
                                                    unsigned int* __restrict__ bufHzero,
                                                    const float* __restrict__ x,
                                                    const _Float16* __restrict__ pW,
                                                    const float* __restrict__ dinv,
                                                    uint4* __restrict__ C,
                                                    int n, int e, int gN, int nE) {
    __shared__ char smem[32768];
    int tid = threadIdx.x;
    int bid = blockIdx.x;
    if (bid >= gN + nE) {                  // layer-1 GEMM from f32 x
        gemm_body<true>(bid - gN - nE, tid, smem, x, pW, dinv, C, n);
        return;
    }
    if (bid < gN) {
        int node = bid * 256 + tid;
        if (node < n) {
            int c = counts[node];
            int o = offs[node];
            int pc = (c + 7) & ~7;
            for (int j = c; j < pc; ++j) er[o + j] = n << 8;   // dummy zero-row byte offset
            if (node == n - 1) offs[n] = o + pc;
        }
        if (bid == 0 && tid < 64) bufAzero[tid] = 0u;  // zero 256 B pad row of bufA
        if (bid == 1 && tid < 64) bufHzero[tid] = 0u;  // zero 256 B pad row of bufH
    } else {
        int base = (bid - gN) * 1024;
        if (base + 1024 <= e) {
            int4 s = ((const int4*)(src + base))[tid];
            int4 d = ((const int4*)(dst + base))[tid];
            int o0 = atomicAdd(&cursor[d.x], 1); er[offs[d.x] + o0] = s.x << 8;
            int o1 = atomicAdd(&cursor[d.y], 1); er[offs[d.y] + o1] = s.y << 8;
            int o2 = atomicAdd(&cursor[d.z], 1); er[offs[d.z] + o2] = s.z << 8;
            int o3 = atomicAdd(&cursor[d.w], 1); er[offs[d.w] + o3] = s.w << 8;
        } else {
            for (int i = base + tid; i < e; i += 256) {
                int dd = dst[i], ss = src[i];
                int o = atomicAdd(&cursor[dd], 1);
                er[offs[dd] + o] = ss << 8;
            }
        }
    }
}

// ---------------- fma_mix accumulate: acc += (f32)h16, 1 instr per element ----------------

__device__ __forceinline__ void acc_row(float4& acc, uint2 q) {
    asm("v_fma_mix_f32 %0, %1, 1.0, %0 op_sel:[0,0,0] op_sel_hi:[1,0,0]" : "+v"(acc.x) : "v"(q.x));
    asm("v_fma_mix_f32 %0, %1, 1.0, %0 op_sel:[1,0,0] op_sel_hi:[1,0,0]" : "+v"(acc.y) : "v"(q.x));
    asm("v_fma_mix_f32 %0, %1, 1.0, %0 op_sel:[0,0,0] op_sel_hi:[1,0,0]" : "+v"(acc.z) : "v"(q.y));
    asm("v_fma_mix_f32 %0, %1, 1.0, %0 op_sel:[1,0,0] op_sel_hi:[1,0,0]" : "+v"(acc.w) : "v"(q.y));
}

// ---------------- CSR aggregation + bias + ReLU + BN (+ optional classifier) ----------------
// 32 lanes/node, 8 nodes/block (round-1 verified structure: high grid parallelism)

template <bool FUSE_CLS>
__global__ __launch_bounds__(256) void k_aggregate(const uint2* __restrict__ Ah,
                                                   const int* __restrict__ offs,
                                                   const int* __restrict__ er,
                                                   const float* __restrict__ dinv,
                                                   const float* __restrict__ bias,
                                                   const float* __restrict__ g,
                                                   const float* __restrict__ be,
                                                   const float* __restrict__ rm,
                                                   const float* __restrict__ rv,
                                                   uint2* __restrict__ Hout,
                                                   const float* __restrict__ Wc,
                                                   const float* __restrict__ bc,
                                                   float* __restrict__ out, int n) {
    int lane = threadIdx.x & 31;
    int node = blockIdx.x * 8 + (threadIdx.x >> 5);
    if (node >= n) return;

    const char* AhB = (const char*)Ah;
    unsigned int l8 = (unsigned int)lane * 8u;

    float4 acc = f4zero();
    // self loop (weight folds to dinv^2); 32-bit offset addressing
    acc_row(acc, *(const uint2*)(AhB + (((unsigned int)node << 8) + l8)));

    int e0 = offs[node], e1 = offs[node + 1];
    for (int e = e0; e < e1; e += 8) {
        int4 ra = *(const int4*)(er + e);
        int4 rb = *(const int4*)(er + e + 4);
        uint2 v0 = *(const uint2*)(AhB + ((unsigned int)ra.x + l8));
        uint2 v1 = *(const uint2*)(AhB + ((unsigned int)ra.y + l8));
        uint2 v2 = *(const uint2*)(AhB + ((unsigned int)ra.z + l8));
        uint2 v3 = *(const uint2*)(AhB + ((unsigned int)ra.w + l8));
        uint2 v4 = *(const uint2*)(AhB + ((unsigned int)rb.x + l8));
        uint2 v5 = *(const uint2*)(AhB + ((unsigned int)rb.y + l8));
        uint2 v6 = *(const uint2*)(AhB + ((unsigned int)rb.z + l8));
        uint2 v7 = *(const uint2*)(AhB + ((unsigned int)rb.w + l8));
        acc_row(acc, v0); acc_row(acc, v1); acc_row(acc, v2); acc_row(acc, v3);
        acc_row(acc, v4); acc_row(acc, v5); acc_row(acc, v6); acc_row(acc, v7);
    }

    float di = dinv[node];
    acc.x *= di; acc.y *= di; acc.z *= di; acc.w *= di;

    float4 b4  = ((const float4*)bias)[lane];
    float4 g4  = ((const float4*)g)[lane];
    float4 be4 = ((const float4*)be)[lane];
    float4 rm4 = ((const float4*)rm)[lane];
    float4 rv4 = ((const float4*)rv)[lane];

    float4 o;
    float v;
    v = fmaxf(acc.x + b4.x, 0.f); o.x = (v - rm4.x) * rsqrtf(rv4.x + BN_EPS) * g4.x + be4.x;
    v = fmaxf(acc.y + b4.y, 0.f); o.y = (v - rm4.y) * rsqrtf(rv4.y + BN_EPS) * g4.y + be4.y;
    v = fmaxf(acc.z + b4.z, 0.f); o.z = (v - rm4.z) * rsqrtf(rv4.z + BN_EPS) * g4.z + be4.z;
    v = fmaxf(acc.w + b4.w, 0.f); o.w = (v - rm4.w) * rsqrtf(rv4.w + BN_EPS) * g4.w + be4.w;

    if (!FUSE_CLS) {
        __half2 p0 = __floats2half2_rn(o.x, o.y);
        __half2 p1 = __floats2half2_rn(o.z, o.w);
        uint2 u;
        u.x = *(unsigned int*)&p0;
        u.y = *(unsigned int*)&p1;
        Hout[(size_t)node * 32 + lane] = u;
    } else {
        const float4* Wv = (const float4*)Wc;
        float4 w01 = Wv[2 * lane];
        float4 w23 = Wv[2 * lane + 1];
        float p0 = o.x * w01.x + o.y * w01.z + o.z * w23.x + o.w * w23.z;
        float p1 = o.x * w01.y + o.y * w01.w + o.z * w23.y + o.w * w23.w;
#pragma unroll
        for (int d = 16; d >= 1; d >>= 1) {
            p0 += __shfl_down(p0, d, 32);
            p1 += __shfl_down(p1, d, 32);
        }
        if (lane == 0) {
            out[node * 2 + 0] = p0 + bc[0];
            out[node * 2 + 1] = p1 + bc[1];
        }
    }
}

// ---------------- launch ----------------

extern "C" void kernel_launch(void* const* d_in, const int* in_sizes, int n_in,
                              void* d_out, int out_size, void* d_ws, size_t ws_size,
                              hipStream_t stream) {
    const float* x   = (const float*)d_in[0];
    const int*   ei  = (const int*)d_in[1];
    const float* W1  = (const float*)d_in[2];
    const float* b1  = (const float*)d_in[3];
    const float* W2  = (const float*)d_in[4];
    const float* b2  = (const float*)d_in[5];
    const float* W3  = (const float*)d_in[6];
    const float* b3  = (const float*)d_in[7];
    const float* g1  = (const float*)d_in[8];
    const float* be1 = (const float*)d_in[9];
    const float* rm1 = (const float*)d_in[10];
    const float* rv1 = (const float*)d_in[11];
    const float* g2  = (const float*)d_in[12];
    const float* be2 = (const float*)d_in[13];
    const float* rm2 = (const float*)d_in[14];
    const float* rv2 = (const float*)d_in[15];
    const float* g3  = (const float*)d_in[16];
    const float* be3 = (const float*)d_in[17];
    const float* rm3 = (const float*)d_in[18];
    const float* rv3 = (const float*)d_in[19];
    const float* Wc  = (const float*)d_in[20];
    const float* bc  = (const float*)d_in[21];
    float* out = (float*)d_out;

    int n = in_sizes[0] / 128;
    int e = in_sizes[1] / 2;
    const int* src = ei;
    const int* dst = ei + e;

    char* ws = (char*)d_ws;
    size_t off = 0;
    auto alloc = [&](size_t bytes) -> char* {
        char* p = ws + off;
        off += (bytes + 255) & ~(size_t)255;
        return p;
    };
    int erCap = e + 8 * n;

    char*      bufA     = (char*) alloc((size_t)(n + 1) * 256);   // ping f16 [n+1][128]
    char*      bufH     = (char*) alloc((size_t)(n + 1) * 256);   // pong f16 [n+1][128]
    float*     dinv     = (float*)alloc((size_t)n * 4);
    int*       cc       = (int*)  alloc((size_t)2 * n * 4);       // counts | cursor
    int*       offs     = (int*)  alloc((size_t)(n + 1) * 4);
    int*       parts    = (int*)  alloc(8192);
    int*       er       = (int*)  alloc((size_t)erCap * 4);
    _Float16*  pW       = (_Float16*)alloc(3 * 16384 * 2);
    (void)ws_size; (void)n_in; (void)out_size;

    int* counts = cc;
    int* cursor = cc + n;

    int nA    = (e + CHUNK - 1) / CHUNK;
    int gN    = (n + 255) / 256;
    int nE    = (e + 1023) / 1024;
    int gGemm = (n + 63) / 64;
    int gAgg  = (n + 7) / 8;
    int len4  = (2 * n + 3) / 4;

    k_zero<<<(len4 + 255) / 256, 256, 0, stream>>>((int4*)cc, len4);
    k_pack_hist<<<24 + nA, 256, 0, stream>>>(W1, W2, W3, pW, dst, counts, e);
    k_scan_dinv<<<(n + 1023) / 1024, 1024, 0, stream>>>(counts, offs, dinv, parts, n);
    k_scan_addp<<<(n + 255) / 256, 256, 0, stream>>>(offs, parts, n);
    k_place_gemm<<<gN + nE + gGemm, 256, 0, stream>>>(
        src, dst, counts, offs, cursor, er,
        (unsigned int*)(bufA + (size_t)n * 256),
        (unsigned int*)(bufH + (size_t)n * 256),
        x, pW, dinv, (uint4*)bufA, n, e, gN, nE);

    // layer 1 aggregate (bufA -> bufH)
    k_aggregate<false><<<gAgg, 256, 0, stream>>>((const uint2*)bufA, offs, er, dinv,
                                                 b1, g1, be1, rm1, rv1, (uint2*)bufH,
                                                 nullptr, nullptr, nullptr, n);
    // layer 2 GEMM (bufH -> bufA), aggregate (bufA -> bufH)
    k_gemm_mfma<<<gGemm, 256, 0, stream>>>(bufH, pW + 16384, dinv, (uint4*)bufA, n);
    k_aggregate<false><<<gAgg, 256, 0, stream>>>((const uint2*)bufA, offs, er, dinv,
                                                 b2, g2, be2, rm2, rv2, (uint2*)bufH,
                                                 nullptr, nullptr, nullptr, n);
    // layer 3 GEMM (bufH -> bufA), aggregate + classifier (bufA -> out)
    k_gemm_mfma<<<gGemm, 256, 0, stream>>>(bufH, pW + 32768, dinv, (uint4*)bufA, n);
    k_aggregate<true><<<gAgg, 256, 0, stream>>>((const uint2*)bufA, offs, er, dinv,
                                                b3, g3, be3, rm3, rv3, nullptr,
                                                Wc, bc, out, n);
}

// Round 5
// 383.498 us; speedup vs baseline: 1.3037x; 1.3037x over previous
//
#include <hip/hip_runtime.h>
#include <hip/hip_fp16.h>

#define BN_EPS 1e-5f
#define CHUNK 4096            // edges per bucketing block (hist and scatter must match)
#define BBITS 7               // 128 nodes per bucket

typedef _Float16 half8 __attribute__((ext_vector_type(8)));
typedef float f32x4 __attribute__((ext_vector_type(4)));

__device__ __forceinline__ float4 f4zero() { return make_float4(0.f, 0.f, 0.f, 0.f); }

// ---------------- K1: packW(all 3) + bucket histogram (blockIdx-split) ----------------

__global__ __launch_bounds__(256) void k_pack_hist(const float* __restrict__ W1,
                                                   const float* __restrict__ W2,
                                                   const float* __restrict__ W3,
                                                   _Float16* __restrict__ pW,
                                                   const int* __restrict__ dst,
                                                   int* __restrict__ tableT,
                                                   int nA, int nbuck, int e) {
    __shared__ int h[1024];
    int tid = threadIdx.x;
    if (blockIdx.x < 24) {            // W pre-pack: f32 [128][128] -> f16 B-fragment order
        int t = blockIdx.x * 256 + tid;   // 0..6143
        int wi = t >> 11;
        int tt = t & 2047;
        const float* W = (wi == 0) ? W1 : ((wi == 1) ? W2 : W3);
        int kc = tt >> 9;
        int rem = tt & 511;
        int ct = rem >> 6;
        int lane = rem & 63;
        int q = lane >> 4;
        int col = ct * 16 + (lane & 15);
        half8 hh;
#pragma unroll
        for (int j = 0; j < 8; ++j)
            hh[j] = (_Float16)W[(kc * 32 + q * 8 + j) * 128 + col];
        *(half8*)(pW + (size_t)t * 8) = hh;
        return;
    }
    int blk = blockIdx.x - 24;
    for (int k = tid; k < 1024; k += 256) h[k] = 0;
    __syncthreads();
    int base = blk * CHUNK;
    if (base + CHUNK <= e && (e & 3) == 0) {
        const int4* d4 = (const int4*)(dst + base);
#pragma unroll
        for (int t = 0; t < CHUNK / 1024; ++t) {
            int4 d = d4[t * 256 + tid];
            atomicAdd(&h[d.x >> BBITS], 1);
            atomicAdd(&h[d.y >> BBITS], 1);
            atomicAdd(&h[d.z >> BBITS], 1);
            atomicAdd(&h[d.w >> BBITS], 1);
        }
    } else {
        for (int i = base + tid; i < e && i < base + CHUNK; i += 256)
            atomicAdd(&h[dst[i] >> BBITS], 1);
    }
    __syncthreads();
    for (int k = tid; k < nbuck; k += 256)
        tableT[(size_t)k * nA + blk] = h[k];
}

// ---------------- K2/K3: 2-op exclusive scan of tableT ----------------

__global__ __launch_bounds__(1024) void k_scan_block(const int* __restrict__ in,
                                                     int* __restrict__ outp,
                                                     int* __restrict__ partials, int len) {
    __shared__ int s[1024];
    int t = threadIdx.x;
    int gid = blockIdx.x * 1024 + t;
    int v = (gid < len) ? in[gid] : 0;
    int x = v;
    s[t] = x;
    __syncthreads();
    for (int d = 1; d < 1024; d <<= 1) {
        int y = (t >= d) ? s[t - d] : 0;
        __syncthreads();
        x += y;
        s[t] = x;
        __syncthreads();
    }
    if (gid < len) outp[gid] = x - v;
    if (t == 1023) partials[blockIdx.x] = x;
}

// each 256-block self-sums the partials it needs (no separate partials-scan kernel)
__global__ __launch_bounds__(256) void k_scan_addp(int* __restrict__ data,
                                                   const int* __restrict__ partials, int len) {
    __shared__ int red[256];
    int tid = threadIdx.x;
    int K = blockIdx.x >> 2;          // number of preceding 1024-segments
    int s = 0;
    for (int t = tid; t < K; t += 256) s += partials[t];
    red[tid] = s;
    __syncthreads();
    for (int d = 128; d > 0; d >>= 1) {
        if (tid < d) red[tid] += red[tid + d];
        __syncthreads();
    }
    int gid = blockIdx.x * 256 + tid;
    if (gid < len) data[gid] += red[0];
}

// ---------------- K4: bucket-grouped COO scatter (LDS cursors) ----------------

__global__ __launch_bounds__(256) void k_bucket_scatter(const int* __restrict__ src,
                                                        const int* __restrict__ dst,
                                                        const int* __restrict__ tableT,
                                                        int2* __restrict__ bed,
                                                        int nA, int nbuck, int e) {
    __shared__ int cur[1024];
    int blk = blockIdx.x, tid = threadIdx.x;
    for (int k = tid; k < nbuck; k += 256)
        cur[k] = tableT[(size_t)k * nA + blk];
    __syncthreads();
    int base = blk * CHUNK;
    if (base + CHUNK <= e && (e & 3) == 0) {
        const int4* s4 = (const int4*)(src + base);
        const int4* d4 = (const int4*)(dst + base);
#pragma unroll
        for (int t = 0; t < CHUNK / 1024; ++t) {
            int4 s = s4[t * 256 + tid];
            int4 d = d4[t * 256 + tid];
            int p0 = atomicAdd(&cur[d.x >> BBITS], 1); bed[p0] = make_int2(s.x, d.x);
            int p1 = atomicAdd(&cur[d.y >> BBITS], 1); bed[p1] = make_int2(s.y, d.y);
            int p2 = atomicAdd(&cur[d.z >> BBITS], 1); bed[p2] = make_int2(s.z, d.z);
            int p3 = atomicAdd(&cur[d.w >> BBITS], 1); bed[p3] = make_int2(s.w, d.w);
        }
    } else {
        for (int i = base + tid; i < e && i < base + CHUNK; i += 256) {
            int d = dst[i];
            int p = atomicAdd(&cur[d >> BBITS], 1);
            bed[p] = make_int2(src[i], d);
        }
    }
}

// ---------------- K5: per-bucket rank + counts + dinv + padded local offsets ----------------

__global__ __launch_bounds__(256) void k_bucket_rank(const int2* __restrict__ bed,
                                                     const int* __restrict__ tableT,
                                                     int* __restrict__ brank,
                                                     int* __restrict__ counts,
                                                     float* __restrict__ dinv,
                                                     int* __restrict__ localOff,
                                                     int* __restrict__ btot,
                                                     int nA, int nbuck, int n, int e) {
    __shared__ int lcnt[128];
    __shared__ int lscan[128];
    int b = blockIdx.x, tid = threadIdx.x;
    if (tid < 128) lcnt[tid] = 0;
    __syncthreads();
    int start = tableT[(size_t)b * nA];
    int end = (b + 1 < nbuck) ? tableT[(size_t)(b + 1) * nA] : e;
    for (int i = start + tid; i < end; i += 256) {
        int2 q = bed[i];
        brank[i] = atomicAdd(&lcnt[q.y & 127], 1);
    }
    __syncthreads();
    int padded = 0;
    if (tid < 128) {
        padded = (lcnt[tid] + 7) & ~7;
        lscan[tid] = padded;
    }
    __syncthreads();
    for (int d = 1; d < 128; d <<= 1) {          // Hillis-Steele inclusive scan over 128
        int y = (tid < 128 && tid >= d) ? lscan[tid - d] : 0;
        __syncthreads();
        if (tid < 128) lscan[tid] += y;
        __syncthreads();
    }
    if (tid < 128) {
        int node = (b << BBITS) + tid;
        if (node < n) {
            int c = lcnt[tid];
            counts[node] = c;
            dinv[node] = rsqrtf((float)(c + 1));
            localOff[node] = lscan[tid] - padded;   // exclusive padded offset within bucket
        }
        if (tid == 127) btot[b] = lscan[127];
    }
}

// ---------------- GEMM body (device): C[n,128](f16) = (A @ W) * dinv[row] ----------------

template <bool AF32>
__device__ __forceinline__ void gemm_body(int bid, int tid, char* smem,
                                          const void* __restrict__ Av,
                                          const _Float16* __restrict__ pW,
                                          const float* __restrict__ dinv,
                                          uint4* __restrict__ C, int n) {
    uint4* sW = (uint4*)smem;
    {
        const uint4* gW = (const uint4*)pW;
#pragma unroll
        for (int i = 0; i < 8; ++i) sW[tid + 256 * i] = gW[tid + 256 * i];
    }
    __syncthreads();

    int wave = tid >> 6, lane = tid & 63;
    int quad = lane >> 4, l16 = lane & 15;
    int row0 = bid * 64 + wave * 16;
    int arow = row0 + l16;
    int arowc = (arow < n) ? arow : (n - 1);

    half8 af[4];
    if (AF32) {
        const float* A = (const float*)Av + (size_t)arowc * 128 + quad * 8;
#pragma unroll
        for (int kc = 0; kc < 4; ++kc) {
            float4 lo = *(const float4*)(A + kc * 32);
            float4 hi = *(const float4*)(A + kc * 32 + 4);
            half8 h;
            h[0] = (_Float16)lo.x; h[1] = (_Float16)lo.y;
            h[2] = (_Float16)lo.z; h[3] = (_Float16)lo.w;
            h[4] = (_Float16)hi.x; h[5] = (_Float16)hi.y;
            h[6] = (_Float16)hi.z; h[7] = (_Float16)hi.w;
            af[kc] = h;
        }
    } else {
        const _Float16* A = (const _Float16*)Av + (size_t)arowc * 128 + quad * 8;
#pragma unroll
        for (int kc = 0; kc < 4; ++kc)
            af[kc] = *(const half8*)(A + kc * 32);
    }

    f32x4 acc[8];
#pragma unroll
    for (int ct = 0; ct < 8; ++ct) acc[ct] = (f32x4){0.f, 0.f, 0.f, 0.f};

#pragma unroll
    for (int kc = 0; kc < 4; ++kc) {
#pragma unroll
        for (int ct = 0; ct < 8; ++ct) {
            half8 bf = *(half8*)&sW[(kc * 8 + ct) * 64 + lane];
            acc[ct] = __builtin_amdgcn_mfma_f32_16x16x32_f16(af[kc], bf, acc[ct], 0, 0, 0);
        }
    }

    __syncthreads();

    _Float16* eb = (_Float16*)smem + wave * 16 * 136;   // 136 halfs = 272 B row stride
    float dv[4];
#pragma unroll
    for (int r = 0; r < 4; ++r) {
        int rr = row0 + quad * 4 + r;
        dv[r] = dinv[(rr < n) ? rr : (n - 1)];
    }
#pragma unroll
    for (int ct = 0; ct < 8; ++ct)
#pragma unroll
        for (int r = 0; r < 4; ++r)
            eb[(quad * 4 + r) * 136 + ct * 16 + l16] = (_Float16)(acc[ct][r] * dv[r]);

#pragma unroll
    for (int i = 0; i < 4; ++i) {
        int linear = i * 64 + lane;
        int r = linear >> 4, c = linear & 15;
        uint4 v = *(uint4*)((char*)eb + r * 272 + c * 16);
        int row = row0 + r;
        if (row < n) C[(size_t)row * 16 + c] = v;
    }
}

__global__ __launch_bounds__(256) void k_gemm_mfma(const void* __restrict__ Av,
                                                   const _Float16* __restrict__ pW,
                                                   const float* __restrict__ dinv,
                                                   uint4* __restrict__ C, int n) {
    __shared__ char smem[32768];
    gemm_body<false>(blockIdx.x, threadIdx.x, smem, Av, pW, dinv, C, n);
}

// ---------------- K6: bucket-total scan (block 0) + layer-1 GEMM (blocks 1..) ----------
// scan_buckets is a 1-block kernel; GEMM1 (needs only dinv + x) fills the other 255 CUs.

__global__ __launch_bounds__(256) void k_scanb_gemm(const int* __restrict__ btot,
                                                    int* __restrict__ bucketBase, int nbuck,
                                                    const float* __restrict__ x,
                                                    const _Float16* __restrict__ pW,
                                                    const float* __restrict__ dinv,
                                                    uint4* __restrict__ C, int n) {
    __shared__ char smem[32768];
    int tid = threadIdx.x;
    if (blockIdx.x > 0) {
        gemm_body<true>(blockIdx.x - 1, tid, smem, x, pW, dinv, C, n);
        return;
    }
    // exclusive scan of btot[0..nbuck) -> bucketBase; bucketBase[nbuck] = total
    int* s = (int*)smem;
    int per = (nbuck + 255) >> 8;          // values per thread
    int base = tid * per;
    int loc[8];                             // per <= 8 for nbuck <= 2048
    int sum = 0;
#pragma unroll 4
    for (int j = 0; j < per; ++j) {
        int v = (base + j < nbuck) ? btot[base + j] : 0;
        loc[j] = sum;
        sum += v;
    }
    int x_ = sum;
    s[tid] = x_;
    __syncthreads();
    for (int d = 1; d < 256; d <<= 1) {
        int y = (tid >= d) ? s[tid - d] : 0;
        __syncthreads();
        x_ += y;
        s[tid] = x_;
        __syncthreads();
    }
    int off = x_ - sum;                     // exclusive prefix of thread sums
#pragma unroll 4
    for (int j = 0; j < per; ++j)
        if (base + j < nbuck) bucketBase[base + j] = off + loc[j];
    if (tid == 255) bucketBase[nbuck] = x_;
}

// ---------------- K7: finalize (blockIdx-split): offs + pad-fill + zero-row | edge place ----
// er stores BYTE offsets (src*256) so k_aggregate does 32-bit addressing.

__global__ __launch_bounds__(256) void k_finalize(const int* __restrict__ counts,
                                                  const int* __restrict__ localOff,
                                                  const int* __restrict__ bucketBase,
                                                  int* __restrict__ offs,
                                                  int* __restrict__ er,
                                                  const int2* __restrict__ bed,
                                                  const int* __restrict__ brank,
                                                  unsigned int* __restrict__ bufAzero,
                                                  int n, int e, int gN, int nbuck) {
    int tid = threadIdx.x;
    if (blockIdx.x < gN) {
        int node = blockIdx.x * 256 + tid;
        if (node < n) {
            int c = counts[node];
            int o = bucketBase[node >> BBITS] + localOff[node];
            offs[node] = o;
            int pc = (c + 7) & ~7;
            for (int j = c; j < pc; ++j) er[o + j] = n << 8;   // dummy zero-row byte offset
        }
        if (node == 0) offs[n] = bucketBase[nbuck];
        if (blockIdx.x == 0 && tid < 64) bufAzero[tid] = 0u;  // zero 256 B pad row of bufA
    } else {
        int i = ((blockIdx.x - gN) * 256 + tid) * 2;
        if (i + 1 < e) {
            int4 q = *(const int4*)(bed + i);      // (s0,d0,s1,d1)
            int2 r = *(const int2*)(brank + i);
            er[bucketBase[q.y >> BBITS] + localOff[q.y] + r.x] = q.x << 8;
            er[bucketBase[q.w >> BBITS] + localOff[q.w] + r.y] = q.z << 8;
        } else if (i < e) {
            int2 q = bed[i];
            er[bucketBase[q.y >> BBITS] + localOff[q.y] + brank[i]] = q.x << 8;
        }
    }
}

// ---------------- fma_mix accumulate: acc += (f32)h16, 1 instr per element ----------------
// uint4 = 8 halfs: q.x -> f0,f1 | q.y -> f2,f3 | q.z -> f4,f5 | q.w -> f6,f7
// aL = f0..f3, aH = f4..f7 (low half-word = even feature, high = odd)

__device__ __forceinline__ void acc_row4(float4& aL, float4& aH, uint4 q) {
    asm("v_fma_mix_f32 %0, %1, 1.0, %0 op_sel:[0,0,0] op_sel_hi:[1,0,0]" : "+v"(aL.x) : "v"(q.x));
    asm("v_fma_mix_f32 %0, %1, 1.0, %0 op_sel:[1,0,0] op_sel_hi:[1,0,0]" : "+v"(aL.y) : "v"(q.x));
    asm("v_fma_mix_f32 %0, %1, 1.0, %0 op_sel:[0,0,0] op_sel_hi:[1,0,0]" : "+v"(aL.z) : "v"(q.y));
    asm("v_fma_mix_f32 %0, %1, 1.0, %0 op_sel:[1,0,0] op_sel_hi:[1,0,0]" : "+v"(aL.w) : "v"(q.y));
    asm("v_fma_mix_f32 %0, %1, 1.0, %0 op_sel:[0,0,0] op_sel_hi:[1,0,0]" : "+v"(aH.x) : "v"(q.z));
    asm("v_fma_mix_f32 %0, %1, 1.0, %0 op_sel:[1,0,0] op_sel_hi:[1,0,0]" : "+v"(aH.y) : "v"(q.z));
    asm("v_fma_mix_f32 %0, %1, 1.0, %0 op_sel:[0,0,0] op_sel_hi:[1,0,0]" : "+v"(aH.z) : "v"(q.w));
    asm("v_fma_mix_f32 %0, %1, 1.0, %0 op_sel:[1,0,0] op_sel_hi:[1,0,0]" : "+v"(aH.w) : "v"(q.w));
}

// ---------------- CSR aggregation + bias + ReLU + BN (+ optional classifier) ----------------
// 16 lanes/node, uint4 (16 B/lane) gathers: same per-feature summation order as the 32-lane
// uint2 version (bit-identical), half the load instructions, 2x outstanding bytes/wave.

template <bool FUSE_CLS>
__global__ __launch_bounds__(256) void k_aggregate(const uint4* __restrict__ Ah,
                                                   const int* __restrict__ offs,
                                                   const int* __restrict__ er,
                                                   const float* __restrict__ dinv,
                                                   const float* __restrict__ bias,
                                                   const float* __restrict__ g,
                                                   const float* __restrict__ be,
                                                   const float* __restrict__ rm,
                                                   const float* __restrict__ rv,
                                                   uint4* __restrict__ Hout,
                                                   const float* __restrict__ Wc,
                                                   const float* __restrict__ bc,
                                                   float* __restrict__ out, int n) {
    int lane = threadIdx.x & 15;
    int node = blockIdx.x * 16 + (threadIdx.x >> 4);
    if (node >= n) return;

    const char* AhB = (const char*)Ah;
    unsigned int l16 = (unsigned int)lane * 16u;

    float4 aL = f4zero(), aH = f4zero();
    // self loop (weight folds to dinv^2); 32-bit offset addressing
    acc_row4(aL, aH, *(const uint4*)(AhB + (((unsigned int)node << 8) + l16)));

    int e0 = offs[node], e1 = offs[node + 1];
    for (int e = e0; e < e1; e += 8) {
        int4 ra = *(const int4*)(er + e);
        int4 rb = *(const int4*)(er + e + 4);
        uint4 v0 = *(const uint4*)(AhB + ((unsigned int)ra.x + l16));
        uint4 v1 = *(const uint4*)(AhB + ((unsigned int)ra.y + l16));
        uint4 v2 = *(const uint4*)(AhB + ((unsigned int)ra.z + l16));
        uint4 v3 = *(const uint4*)(AhB + ((unsigned int)ra.w + l16));
        uint4 v4 = *(const uint4*)(AhB + ((unsigned int)rb.x + l16));
        uint4 v5 = *(const uint4*)(AhB + ((unsigned int)rb.y + l16));
        uint4 v6 = *(const uint4*)(AhB + ((unsigned int)rb.z + l16));
        uint4 v7 = *(const uint4*)(AhB + ((unsigned int)rb.w + l16));
        acc_row4(aL, aH, v0); acc_row4(aL, aH, v1); acc_row4(aL, aH, v2); acc_row4(aL, aH, v3);
        acc_row4(aL, aH, v4); acc_row4(aL, aH, v5); acc_row4(aL, aH, v6); acc_row4(aL, aH, v7);
    }

    float di = dinv[node];
    aL.x *= di; aL.y *= di; aL.z *= di; aL.w *= di;
    aH.x *= di; aH.y *= di; aH.z *= di; aH.w *= di;

    // lane covers features [8*lane, 8*lane+8) -> float4 indices 2*lane, 2*lane+1
    float4 bL  = ((const float4*)bias)[2 * lane], bH  = ((const float4*)bias)[2 * lane + 1];
    float4 gL  = ((const float4*)g)[2 * lane],    gH  = ((const float4*)g)[2 * lane + 1];
    float4 beL = ((const float4*)be)[2 * lane],   beH = ((const float4*)be)[2 * lane + 1];
    float4 rmL = ((const float4*)rm)[2 * lane],   rmH = ((const float4*)rm)[2 * lane + 1];
    float4 rvL = ((const float4*)rv)[2 * lane],   rvH = ((const float4*)rv)[2 * lane + 1];

    float4 oL, oH;
    float v;
    v = fmaxf(aL.x + bL.x, 0.f); oL.x = (v - rmL.x) * rsqrtf(rvL.x + BN_EPS) * gL.x + beL.x;
    v = fmaxf(aL.y + bL.y, 0.f); oL.y = (v - rmL.y) * rsqrtf(rvL.y + BN_EPS) * gL.y + beL.y;
    v = fmaxf(aL.z + bL.z, 0.f); oL.z = (v - rmL.z) * rsqrtf(rvL.z + BN_EPS) * gL.z + beL.z;
    v = fmaxf(aL.w + bL.w, 0.f); oL.w = (v - rmL.w) * rsqrtf(rvL.w + BN_EPS) * gL.w + beL.w;
    v = fmaxf(aH.x + bH.x, 0.f); oH.x = (v - rmH.x) * rsqrtf(rvH.x + BN_EPS) * gH.x + beH.x;
    v = fmaxf(aH.y + bH.y, 0.f); oH.y = (v - rmH.y) * rsqrtf(rvH.y + BN_EPS) * gH.y + beH.y;
    v = fmaxf(aH.z + bH.z, 0.f); oH.z = (v - rmH.z) * rsqrtf(rvH.z + BN_EPS) * gH.z + beH.z;
    v = fmaxf(aH.w + bH.w, 0.f); oH.w = (v - rmH.w) * rsqrtf(rvH.w + BN_EPS) * gH.w + beH.w;

    if (!FUSE_CLS) {
        __half2 p0 = __floats2half2_rn(oL.x, oL.y);
        __half2 p1 = __floats2half2_rn(oL.z, oL.w);
        __half2 p2 = __floats2half2_rn(oH.x, oH.y);
        __half2 p3 = __floats2half2_rn(oH.z, oH.w);
        uint4 u;
        u.x = *(unsigned int*)&p0;
        u.y = *(unsigned int*)&p1;
        u.z = *(unsigned int*)&p2;
        u.w = *(unsigned int*)&p3;
        Hout[(size_t)node * 16 + lane] = u;
    } else {
        const float4* Wv = (const float4*)Wc;   // Wc[f][2]: float4 i = features 2i,2i+1
        float4 w0 = Wv[4 * lane];
        float4 w1 = Wv[4 * lane + 1];
        float4 w2 = Wv[4 * lane + 2];
        float4 w3 = Wv[4 * lane + 3];
        float p0 = oL.x * w0.x + oL.y * w0.z + oL.z * w1.x + oL.w * w1.z
                 + oH.x * w2.x + oH.y * w2.z + oH.z * w3.x + oH.w * w3.z;
        float p1 = oL.x * w0.y + oL.y * w0.w + oL.z * w1.y + oL.w * w1.w
                 + oH.x * w2.y + oH.y * w2.w + oH.z * w3.y + oH.w * w3.w;
#pragma unroll
        for (int d = 8; d >= 1; d >>= 1) {
            p0 += __shfl_down(p0, d, 16);
            p1 += __shfl_down(p1, d, 16);
        }
        if (lane == 0) {
            out[node * 2 + 0] = p0 + bc[0];
            out[node * 2 + 1] = p1 + bc[1];
        }
    }
}

// ---------------- launch ----------------

extern "C" void kernel_launch(void* const* d_in, const int* in_sizes, int n_in,
                              void* d_out, int out_size, void* d_ws, size_t ws_size,
                              hipStream_t stream) {
    const float* x   = (const float*)d_in[0];
    const int*   ei  = (const int*)d_in[1];
    const float* W1  = (const float*)d_in[2];
    const float* b1  = (const float*)d_in[3];
    const float* W2  = (const float*)d_in[4];
    const float* b2  = (const float*)d_in[5];
    const float* W3  = (const float*)d_in[6];
    const float* b3  = (const float*)d_in[7];
    const float* g1  = (const float*)d_in[8];
    const float* be1 = (const float*)d_in[9];
    const float* rm1 = (const float*)d_in[10];
    const float* rv1 = (const float*)d_in[11];
    const float* g2  = (const float*)d_in[12];
    const float* be2 = (const float*)d_in[13];
    const float* rm2 = (const float*)d_in[14];
    const float* rv2 = (const float*)d_in[15];
    const float* g3  = (const float*)d_in[16];
    const float* be3 = (const float*)d_in[17];
    const float* rm3 = (const float*)d_in[18];
    const float* rv3 = (const float*)d_in[19];
    const float* Wc  = (const float*)d_in[20];
    const float* bc  = (const float*)d_in[21];
    float* out = (float*)d_out;

    int n = in_sizes[0] / 128;
    int e = in_sizes[1] / 2;
    const int* src = ei;
    const int* dst = ei + e;

    char* ws = (char*)d_ws;
    size_t off = 0;
    auto alloc = [&](size_t bytes) -> char* {
        char* p = ws + off;
        off += (bytes + 255) & ~(size_t)255;
        return p;
    };
    int nA    = (e + CHUNK - 1) / CHUNK;
    int nbuck = (n + (1 << BBITS) - 1) >> BBITS;
    int tlen  = nbuck * nA;
    int erCap = e + 8 * n;

    char*      bufA     = (char*) alloc((size_t)(n + 1) * 256);   // GEMM out f16 [n+1][128]
    char*      bufH     = (char*) alloc((size_t)n * 256);         // H f16; prep scratch alias
    float*     dinv     = (float*)alloc((size_t)n * 4);
    int*       counts   = (int*)  alloc((size_t)n * 4);
    int*       offs     = (int*)  alloc((size_t)(n + 1) * 4);
    int*       localOff = (int*)  alloc((size_t)n * 4);
    int*       btot     = (int*)  alloc((size_t)(nbuck + 1) * 4);
    int*       bktBase  = (int*)  alloc((size_t)(nbuck + 1) * 4);
    int*       tableT   = (int*)  alloc((size_t)(tlen + 1) * 4);
    int*       parts    = (int*)  alloc(8192);
    int*       er       = (int*)  alloc((size_t)erCap * 4);
    _Float16*  pW       = (_Float16*)alloc(3 * 16384 * 2);
    (void)ws_size; (void)n_in; (void)out_size;

    // bed + brank alias bufH (dead until first aggregate; consumed by k_finalize)
    int2* bed   = (int2*)bufH;                       // e*8 = 12.8 MB
    int*  brank = (int*)(bufH + (size_t)e * 8);      // e*4 = 6.4 MB  (total 19.2 < 25.6 MB)

    int gN  = (n + 255) / 256;
    int nbT = (tlen + 1023) / 1024;
    int gGemm = (n + 63) / 64;
    int gAgg  = (n + 15) / 16;

    k_pack_hist<<<24 + nA, 256, 0, stream>>>(W1, W2, W3, pW, dst, tableT, nA, nbuck, e);
    k_scan_block<<<nbT, 1024, 0, stream>>>(tableT, tableT, parts, tlen);
    k_scan_addp<<<(tlen + 255) / 256, 256, 0, stream>>>(tableT, parts, tlen);
    k_bucket_scatter<<<nA, 256, 0, stream>>>(src, dst, tableT, bed, nA, nbuck, e);
    k_bucket_rank<<<nbuck, 256, 0, stream>>>(bed, tableT, brank, counts, dinv, localOff,
                                             btot, nA, nbuck, n, e);
    // bucket scan (1 block) + layer-1 GEMM (needs only dinv + x) in one launch
    k_scanb_gemm<<<1 + gGemm, 256, 0, stream>>>(btot, bktBase, nbuck,
                                                x, pW, dinv, (uint4*)bufA, n);
    int gP = gN + (e / 2 + 255) / 256 + 1;
    k_finalize<<<gP, 256, 0, stream>>>(counts, localOff, bktBase, offs, er, bed, brank,
                                       (unsigned int*)(bufA + (size_t)n * 256), n, e, gN, nbuck);

    // layer 1 aggregate (bufA -> bufH)
    k_aggregate<false><<<gAgg, 256, 0, stream>>>((const uint4*)bufA, offs, er, dinv,
                                                 b1, g1, be1, rm1, rv1, (uint4*)bufH,
                                                 nullptr, nullptr, nullptr, n);
    // layer 2 GEMM (bufH -> bufA), aggregate (bufA -> bufH)
    k_gemm_mfma<<<gGemm, 256, 0, stream>>>(bufH, pW + 16384, dinv, (uint4*)bufA, n);
    k_aggregate<false><<<gAgg, 256, 0, stream>>>((const uint4*)bufA, offs, er, dinv,
                                                 b2, g2, be2, rm2, rv2, (uint4*)bufH,
                                                 nullptr, nullptr, nullptr, n);
    // layer 3 GEMM (bufH -> bufA), aggregate + classifier (bufA -> out)
    k_gemm_mfma<<<gGemm, 256, 0, stream>>>(bufH, pW + 32768, dinv, (uint4*)bufA, n);
    k_aggregate<true><<<gAgg, 256, 0, stream>>>((const uint4*)bufA, offs, er, dinv,
                                                b3, g3, be3, rm3, rv3, nullptr,
                                                Wc, bc, out, n);
}